// Round 6
// baseline (1147.229 us; speedup 1.0000x reference)
//
#include <hip/hip_runtime.h>
#include <hip/hip_bf16.h>

using short8 = __attribute__((ext_vector_type(8))) short;
using short4v = __attribute__((ext_vector_type(4))) short;
using f32x4 = __attribute__((ext_vector_type(4))) float;

#define MFMA(a, b, c) __builtin_amdgcn_mfma_f32_16x16x32_bf16((a), (b), (c), 0, 0, 0)

// LDS map (bytes). All region offsets 16B-aligned; all row strides multiples of 16B
// (round-4 lesson: non-16B strides break ds_read_b128 on odd rows).
//  [0,     32768)  xb   : x bf16 [64][256], rows 512B, XOR-swizzle byte^=(row&7)<<4
//  [32768, 43008)  q|k  : q [64 tok][40 elem] (5120B), k at +5120
//                  P overlays q+k after B1.5: [64 qtok][72 elem] = 9216B
//  [43008, 47616)  vt   : [32 dim][72 elem] (4608B), cols = tokens
//  [47616, 47872)  rinv : 64 f32 (per-token 1/sumexp for current head)
//  [47872, 80640)  ob   : O bf16 [64][256], swizzled like xb
// total 80640B -> 2 blocks/CU (2*80640 = 161280 <= 163840)
#define XBOFF   0
#define QOFF    32768
#define KOFF    37888
#define POFF    32768
#define VTOFF   43008
#define RINVOFF 47616
#define OBOFF   47872
#define LDSBYTES 80640

__global__ void prep_weights(const float* __restrict__ qkv_w, const float* __restrict__ proj_w,
                             __hip_bfloat16* __restrict__ wq_t, __hip_bfloat16* __restrict__ wp_t) {
    int j = blockIdx.x, t = threadIdx.x;
    if (j < 768) {
        wq_t[j * 256 + t] = __float2bfloat16(qkv_w[t * 768 + j]);
    } else {
        int j2 = j - 768;
        wp_t[j2 * 256 + t] = __float2bfloat16(proj_w[t * 256 + j2]);
    }
}

__global__ __launch_bounds__(512, 4) void swin_fused(
    const float* __restrict__ x, const float* __restrict__ mask,
    const float* __restrict__ qkv_b, const float* __restrict__ proj_b,
    const float* __restrict__ rpb,
    const __hip_bfloat16* __restrict__ wq_t, const __hip_bfloat16* __restrict__ wp_t,
    float* __restrict__ out)
{
    __shared__ __align__(16) char lds[LDSBYTES];

    const int tid = threadIdx.x;
    const int wv = tid >> 6;      // wave 0..7
    const int lane = tid & 63;
    const int lg = lane >> 4;     // 0..3
    const int li = lane & 15;     // 0..15
    const int b = blockIdx.x;
    const int w = b & 63;         // window index for mask
    const int mw = wv & 3;        // wave's m-tile (16 tokens)
    const int cb = wv >> 2;       // wave's column-block / d-half

    // ---- phase 1: x -> xb (bf16, swizzled). One row per wave per iter. ----
    {
#pragma unroll
        for (int it = 0; it < 8; ++it) {
            int row = it * 8 + wv;
            float4 v = *(const float4*)(x + (size_t)b * 16384 + row * 256 + lane * 4);
            __hip_bfloat16 t[4] = {__float2bfloat16(v.x), __float2bfloat16(v.y),
                                   __float2bfloat16(v.z), __float2bfloat16(v.w)};
            *(short4v*)(lds + XBOFF + row * 512 + ((lane * 8) ^ (wv << 4))) = *(const short4v*)t;
        }
    }
    __syncthreads();

    // ---- hoisted per-lane constants for S-waves (head-independent) ----
    float mb[4][4];         // window mask values
    unsigned idxp[4];       // rel-pos-bias indices, 4x u8 packed per nt
    if (wv < 4) {
        const float* mwp = mask + w * 4096 + (wv * 16 + lg * 4) * 64;
#pragma unroll
        for (int nt = 0; nt < 4; ++nt) {
            unsigned p = 0;
#pragma unroll
            for (int r = 0; r < 4; ++r) {
                mb[nt][r] = mwp[r * 64 + nt * 16 + li];
                int m = wv * 16 + lg * 4 + r;
                int n = nt * 16 + li;
                unsigned idx = (unsigned)(((m >> 3) - (n >> 3) + 7) * 15 + ((m & 7) - (n & 7) + 7));
                p |= idx << (8 * r);
            }
            idxp[nt] = p;
        }
    }

    const float scale = 0.17677669529663687f; // 32^-0.5, folded into q

    // ================= head loop =================
    for (int h = 0; h < 8; ++h) {
        // ---- QKV: wave computes m-tile mw x 3 column-tiles (ct = 3*cb + j) ----
        f32x4 acc[3] = {(f32x4)0.f, (f32x4)0.f, (f32x4)0.f};
        const int arow = mw * 16 + li;
#pragma unroll
        for (int kt = 0; kt < 8; ++kt) {
            short8 af = *(const short8*)(lds + XBOFF + arow * 512 +
                                         ((kt * 64 + lg * 16) ^ ((li & 7) << 4)));
#pragma unroll
            for (int j = 0; j < 3; ++j) {
                int ct = 3 * cb + j;
                int wcol = (ct >> 1) * 256 + h * 32 + (ct & 1) * 16 + li;
                short8 bf = *(const short8*)(wq_t + wcol * 256 + kt * 32 + lg * 8);
                acc[j] = MFMA(af, bf, acc[j]);
            }
        }
        // scatter epilogue to q / k / vt
        {
            const int tok = mw * 16 + lg * 4;
#pragma unroll
            for (int j = 0; j < 3; ++j) {
                int ct = 3 * cb + j;
                int sel = ct >> 1, c16 = ct & 1;
                float bias = qkv_b[sel * 256 + h * 32 + c16 * 16 + li];
                if (sel == 0) {
#pragma unroll
                    for (int r = 0; r < 4; ++r) {
                        __hip_bfloat16 tb = __float2bfloat16((acc[j][r] + bias) * scale);
                        *(__hip_bfloat16*)(lds + QOFF + (tok + r) * 80 + (c16 * 16 + li) * 2) = tb;
                    }
                } else if (sel == 1) {
#pragma unroll
                    for (int r = 0; r < 4; ++r) {
                        __hip_bfloat16 tb = __float2bfloat16(acc[j][r] + bias);
                        *(__hip_bfloat16*)(lds + KOFF + (tok + r) * 80 + (c16 * 16 + li) * 2) = tb;
                    }
                } else {
                    short4v t4;
#pragma unroll
                    for (int r = 0; r < 4; ++r) {
                        __hip_bfloat16 tb = __float2bfloat16(acc[j][r] + bias);
                        t4[r] = *reinterpret_cast<short*>(&tb);
                    }
                    // vt[dim][tok]: 4 consecutive tokens packed -> ds_write_b64
                    *(short4v*)(lds + VTOFF + (c16 * 16 + li) * 144 + tok * 2) = t4;
                }
            }
        }
        __syncthreads(); // B1: q/k/vt ready

        // ---- S = q k^T + bias + mask (waves 0-3, full rows in-wave) ----
        f32x4 s[4];
        if (wv < 4) {
            short8 aq = *(const short8*)(lds + QOFF + (wv * 16 + li) * 80 + lg * 16);
#pragma unroll
            for (int nt = 0; nt < 4; ++nt) {
                short8 bk = *(const short8*)(lds + KOFF + (nt * 16 + li) * 80 + lg * 16);
                s[nt] = MFMA(aq, bk, (f32x4)0.f);
            }
            const float* rpbh = rpb + h;
#pragma unroll
            for (int nt = 0; nt < 4; ++nt)
#pragma unroll
                for (int r = 0; r < 4; ++r) {
                    int idx = (int)((idxp[nt] >> (8 * r)) & 255u);
                    s[nt][r] += rpbh[idx * 8] + mb[nt][r];
                }
        }
        __syncthreads(); // B1.5: ALL waves' q/k fragment reads done -> P may overlay q+k

        if (wv < 4) {
#pragma unroll
            for (int r = 0; r < 4; ++r) {
                float mx = fmaxf(fmaxf(s[0][r], s[1][r]), fmaxf(s[2][r], s[3][r]));
#pragma unroll
                for (int off = 1; off < 16; off <<= 1) mx = fmaxf(mx, __shfl_xor(mx, off));
                float sum = 0.f;
#pragma unroll
                for (int nt = 0; nt < 4; ++nt) {
                    float p = __expf(s[nt][r] - mx);
                    s[nt][r] = p;
                    sum += p;
                }
#pragma unroll
                for (int off = 1; off < 16; off <<= 1) sum += __shfl_xor(sum, off);
                int qtok = wv * 16 + lg * 4 + r;
                if (li == 0) *(float*)(lds + RINVOFF + qtok * 4) = 1.f / sum;
#pragma unroll
                for (int nt = 0; nt < 4; ++nt) {
                    __hip_bfloat16 tb = __float2bfloat16(s[nt][r]);
                    *(__hip_bfloat16*)(lds + POFF + qtok * 144 + (nt * 16 + li) * 2) = tb;
                }
            }
        }
        __syncthreads(); // B2: P + rinv ready

        // ---- PV: all 8 waves, tile (m=mw, d-half=cb) ----
        {
            f32x4 o = (f32x4)0.f;
#pragma unroll
            for (int kt = 0; kt < 2; ++kt) {
                short8 pa = *(const short8*)(lds + POFF + (mw * 16 + li) * 144 + kt * 64 + lg * 16);
                short8 vb = *(const short8*)(lds + VTOFF + (cb * 16 + li) * 144 + kt * 64 + lg * 16);
                o = MFMA(pa, vb, o);
            }
#pragma unroll
            for (int r = 0; r < 4; ++r) {
                int qtok = mw * 16 + lg * 4 + r;
                float rv = *(const float*)(lds + RINVOFF + qtok * 4);
                __hip_bfloat16 tb = __float2bfloat16(o[r] * rv);
                int col = h * 32 + cb * 16 + li;
                *(__hip_bfloat16*)(lds + OBOFF + qtok * 512 + ((col * 2) ^ ((qtok & 7) << 4))) = tb;
            }
        }
        __syncthreads(); // B3: PV done; q/k/vt/P/rinv free for next head; (h=7: ob ready)
    }

    // ---- proj: wave wv -> out cols wv*32 .. +31 ----
    {
        f32x4 po[4][2] = {{(f32x4)0.f, (f32x4)0.f}, {(f32x4)0.f, (f32x4)0.f},
                          {(f32x4)0.f, (f32x4)0.f}, {(f32x4)0.f, (f32x4)0.f}};
#pragma unroll
        for (int kt = 0; kt < 8; ++kt) {
            short8 a[4];
#pragma unroll
            for (int mt = 0; mt < 4; ++mt)
                a[mt] = *(const short8*)(lds + OBOFF + (mt * 16 + li) * 512 +
                                         ((kt * 64 + lg * 16) ^ ((li & 7) << 4)));
#pragma unroll
            for (int n = 0; n < 2; ++n) {
                int col = wv * 32 + n * 16 + li;
                short8 bb = *(const short8*)(wp_t + col * 256 + kt * 32 + lg * 8);
#pragma unroll
                for (int mt = 0; mt < 4; ++mt) po[mt][n] = MFMA(a[mt], bb, po[mt][n]);
            }
        }
        float* op = out + (size_t)b * 16384;
#pragma unroll
        for (int n = 0; n < 2; ++n) {
            int col = wv * 32 + n * 16 + li;
            float pb = proj_b[col];
#pragma unroll
            for (int mt = 0; mt < 4; ++mt)
#pragma unroll
                for (int r = 0; r < 4; ++r)
                    op[(mt * 16 + lg * 4 + r) * 256 + col] = po[mt][n][r] + pb;
        }
    }
}

extern "C" void kernel_launch(void* const* d_in, const int* in_sizes, int n_in,
                              void* d_out, int out_size, void* d_ws, size_t ws_size,
                              hipStream_t stream) {
    const float* x      = (const float*)d_in[0];
    const float* mask   = (const float*)d_in[1];
    const float* qkv_w  = (const float*)d_in[2];
    const float* qkv_b  = (const float*)d_in[3];
    const float* proj_w = (const float*)d_in[4];
    const float* proj_b = (const float*)d_in[5];
    const float* rpb    = (const float*)d_in[6];

    __hip_bfloat16* wq_t = (__hip_bfloat16*)d_ws;          // [768][256] bf16
    __hip_bfloat16* wp_t = wq_t + 768 * 256;               // [256][256] bf16

    prep_weights<<<1024, 256, 0, stream>>>(qkv_w, proj_w, wq_t, wp_t);
    swin_fused<<<4096, 512, 0, stream>>>(x, mask, qkv_b, proj_b, rpb, wq_t, wp_t, (float*)d_out);
}